// Round 7
// baseline (75.914 us; speedup 1.0000x reference)
//
#include <hip/hip_runtime.h>
#include <stdint.h>

// ---------------------------------------------------------------------------
// TopK: scores = (embs @ scorer)/sum(scorer) + mask; top-k rows; out = rows^T
// Ordering matches numpy/OpenBLAS sgemv_t fp32 bits exactly (verified
// R3/R5/R6, absmax=0): per row, 8 mod-8 fma chains (chain c sums elements
// c, c+8, ... ascending), reduced as ((L0+L4)+(L1+L5)) + ((L2+L6)+(L3+L7)).
// R7: pipeline collapsed 6 -> 4 kernels (launch/drain overhead + barrier
// storm in the old k2 was ~1/3 of total):
//   k1 : thread-per-row scoring, no atomics (R6, unchanged).
//   kB : ONE single-block kernel = histogram (4 LDS sub-hists, 128KB) +
//        barrier-light suffix scan (3 barriers) + bucket find + wave-ballot
//        compaction (keys re-read is L2-hot on the same XCD).
//   k4 : exact rank-by-count, 16 candidates/block.
//   k5 : gather + transpose via padded LDS tiles.
// d_out holds keys during the pipeline; k5 overwrites all of d_out.
// ws use: 41KB (hdr/ckey/cidx/oidx). No state carried across calls.
// ---------------------------------------------------------------------------

#define NBINS 8192   // 13-bit radix: sign + exp(8) + mantissa(4)
#define BIN_SHIFT 19
#define CAP 4096     // candidates: k + boundary bin (~600) << CAP
#define SUBH 4

__device__ __forceinline__ uint32_t f2key(float f) {
  uint32_t b = __float_as_uint(f);
  return (b & 0x80000000u) ? ~b : (b | 0x80000000u);
}

// ---- kernel 1: thread-per-row fp32 dot in OpenBLAS sgemv_t order ----------
// Each thread streams its own 1KB row (64 float4; full 64B-line use via L1
// reuse across j). No atomics, no main-loop barriers.
__global__ __launch_bounds__(256) void k1_scores(
    const float* __restrict__ embs, const float* __restrict__ mask,
    const float* __restrict__ scorer,
    uint32_t* __restrict__ keys, int N) {
  __shared__ float sw[256];
  __shared__ float Ssh;
  int t = threadIdx.x;
  sw[t] = scorer[t];  // F == 256
  __syncthreads();
  if (t < 64) {
    double s = 0.0;
    for (int j = t; j < 256; j += 64) s += (double)sw[j];
#pragma unroll
    for (int off = 32; off >= 1; off >>= 1) s += __shfl_xor(s, off, 64);
    if (t == 0) Ssh = (float)s;  // f64 sum: order-independent at f32 grain
  }
  __syncthreads();
  float S = Ssh;
  int row = blockIdx.x * 256 + t;
  if (row >= N) return;
  const float4* e4 = (const float4*)embs + (size_t)row * 64;
  const float4* w4 = (const float4*)sw;
  float L[8];
#pragma unroll
  for (int i = 0; i < 8; ++i) L[i] = 0.f;
#pragma unroll 16
  for (int j = 0; j < 64; ++j) {
    float4 v = e4[j];
    float4 w = w4[j];           // LDS broadcast (all lanes same addr)
    // element 4j+i belongs to chain 4*(j&1)+i; j ascending = k ascending
    if ((j & 1) == 0) {
      L[0] = fmaf(v.x, w.x, L[0]);
      L[1] = fmaf(v.y, w.y, L[1]);
      L[2] = fmaf(v.z, w.z, L[2]);
      L[3] = fmaf(v.w, w.w, L[3]);
    } else {
      L[4] = fmaf(v.x, w.x, L[4]);
      L[5] = fmaf(v.y, w.y, L[5]);
      L[6] = fmaf(v.z, w.z, L[6]);
      L[7] = fmaf(v.w, w.w, L[7]);
    }
  }
  float m0 = L[0] + L[4];
  float m1 = L[1] + L[5];
  float m2 = L[2] + L[6];
  float m3 = L[3] + L[7];
  float dot = (m0 + m1) + (m2 + m3);
  float score = dot / S + mask[row];
  keys[row] = f2key(score);
}

// ---- kernel B: single block — hist + suffix-scan + find + compact ---------
__global__ __launch_bounds__(1024) void kB_select(
    const uint32_t* __restrict__ keys, uint32_t* __restrict__ hdr,
    uint32_t* __restrict__ ckey, uint32_t* __restrict__ cidx, int N, int k) {
  __shared__ uint32_t h[SUBH][NBINS];  // 128 KB
  __shared__ uint32_t wtot[16];
  __shared__ uint32_t wsuf[16];
  __shared__ uint32_t sB;
  __shared__ uint32_t scnt;
  int t = threadIdx.x;
  int lane = t & 63, wave = t >> 6;
  for (int i = t; i < SUBH * NBINS; i += 1024) ((uint32_t*)h)[i] = 0u;
  if (t == 0) scnt = 0u;
  __syncthreads();
  // --- histogram (4 sub-hists cut hot-bin LDS-atomic serialization) ---
  int sub = t & (SUBH - 1);
  const uint4* q4 = (const uint4*)keys;
  int n4 = N >> 2;
  for (int i = t; i < n4; i += 1024) {
    uint4 v = q4[i];
    atomicAdd(&h[sub][v.x >> BIN_SHIFT], 1u);
    atomicAdd(&h[sub][v.y >> BIN_SHIFT], 1u);
    atomicAdd(&h[sub][v.z >> BIN_SHIFT], 1u);
    atomicAdd(&h[sub][v.w >> BIN_SHIFT], 1u);
  }
  for (int i = (n4 << 2) + t; i < N; i += 1024)
    atomicAdd(&h[sub][keys[i] >> BIN_SHIFT], 1u);
  __syncthreads();
  // --- merge 8 bins/thread into registers ---
  uint32_t rb[8];
  uint32_t p8 = 0;
#pragma unroll
  for (int j = 0; j < 8; ++j) {
    int bin = t * 8 + j;
    uint32_t s = h[0][bin] + h[1][bin] + h[2][bin] + h[3][bin];
    rb[j] = s;
    p8 += s;
  }
  // --- wave-internal inclusive suffix scan (no barriers) ---
  uint32_t x = p8;
#pragma unroll
  for (int off = 1; off < 64; off <<= 1) {
    uint32_t v = __shfl_down(x, off, 64);
    if (lane + off < 64) x += v;
  }
  if (lane == 0) wtot[wave] = x;
  __syncthreads();
  if (t < 16) {
    uint32_t y = wtot[t];
#pragma unroll
    for (int off = 1; off < 16; off <<= 1) {
      uint32_t v = __shfl_down(y, off, 64);
      if (t + off < 16) y += v;
    }
    wsuf[t] = y - wtot[t];  // exclusive suffix over wave totals
  }
  __syncthreads();
  uint32_t St = x + wsuf[wave];   // count of keys with bin >= 8t
  uint32_t above = St - p8;       // count with bin >= 8t+8
  if (above < (uint32_t)k && St >= (uint32_t)k) {  // unique thread
    uint32_t cum = above;
    for (int jj = 7; jj >= 0; --jj) {
      if (cum + rb[jj] >= (uint32_t)k) { sB = (uint32_t)(t * 8 + jj); break; }
      cum += rb[jj];
    }
  }
  __syncthreads();
  // --- compact candidates (bin >= B); keys are L2-hot from pass 1 ---
  uint32_t B = sB;
  for (int i = t; i < N; i += 1024) {
    uint32_t key = keys[i];
    bool pred = (key >> BIN_SHIFT) >= B;
    unsigned long long ball = __ballot(pred);
    uint32_t prefix = (uint32_t)__popcll(ball & ((1ull << lane) - 1ull));
    uint32_t wn = (uint32_t)__popcll(ball);
    uint32_t base = 0;
    if (lane == 0 && wn) base = atomicAdd(&scnt, wn);
    base = __shfl(base, 0, 64);  // lane 0 always active (actives are prefix)
    if (pred) {
      uint32_t pos = base + prefix;
      if (pos < CAP) { ckey[pos] = key; cidx[pos] = (uint32_t)i; }
    }
  }
  __syncthreads();
  if (t == 0) hdr[2] = scnt;  // candidate count C for k4
}

// ---- kernel 4: exact rank, 4 candidates/wave, 16/block --------------------
__global__ __launch_bounds__(256) void k4_rank(
    const uint32_t* __restrict__ ckey, const uint32_t* __restrict__ cidx,
    const uint32_t* __restrict__ hdr, uint32_t* __restrict__ oidx, int k) {
  __shared__ uint32_t lk[CAP];
  __shared__ uint32_t li[CAP];
  uint32_t C = hdr[2];
  if (C > CAP) C = CAP;
  uint32_t base = blockIdx.x * 16u;
  if (base >= C) return;
  for (uint32_t j = threadIdx.x; j < C; j += 256u) {
    lk[j] = ckey[j];
    li[j] = cidx[j];
  }
  __syncthreads();
  int wave = threadIdx.x >> 6, lane = threadIdx.x & 63;
  uint32_t g0 = base + wave * 4u;
  uint32_t mk[4], mi[4], cnt[4];
#pragma unroll
  for (int q = 0; q < 4; ++q) {
    uint32_t g = g0 + q;
    bool valid = g < C;
    mk[q] = valid ? lk[g] : 0u;
    mi[q] = valid ? li[g] : 0xFFFFFFFFu;
    cnt[q] = 0u;
  }
  for (uint32_t j = lane; j < C; j += 64u) {
    uint32_t kj = lk[j], ij = li[j];
#pragma unroll
    for (int q = 0; q < 4; ++q)
      cnt[q] += (kj > mk[q] || (kj == mk[q] && ij < mi[q])) ? 1u : 0u;
  }
#pragma unroll
  for (int q = 0; q < 4; ++q) {
#pragma unroll
    for (int off = 32; off >= 1; off >>= 1) cnt[q] += __shfl_xor(cnt[q], off, 64);
  }
  if (lane == 0) {
#pragma unroll
    for (int q = 0; q < 4; ++q) {
      uint32_t g = g0 + q;
      if (g < C && cnt[q] < (uint32_t)k) oidx[cnt[q]] = mi[q];
    }
  }
}

// ---- kernel 5: gather + transpose; 16 ranks x 128 feats per block ----------
__global__ __launch_bounds__(256) void k5_gather(
    const float* __restrict__ embs, const uint32_t* __restrict__ oidx,
    float* __restrict__ out, int k) {
  __shared__ float tile[16 * 132];
  __shared__ uint32_t sidx[16];
  int t = threadIdx.x;
  int r0 = blockIdx.x * 16;
  int fb = blockIdx.y * 128;
  if (t < 16) sidx[t] = (r0 + t < k) ? oidx[r0 + t] : 0u;
  __syncthreads();
  const float4* e4 = (const float4*)embs;
#pragma unroll
  for (int m = 0; m < 2; ++m) {      // 2*256 = 512 f4 = 16 rows x 32 f4
    int flat = m * 256 + t;
    int rr = flat >> 5;
    int cc4 = flat & 31;
    float4 v = e4[(size_t)sidx[rr] * 64 + (fb >> 2) + cc4];
    float* dst = &tile[rr * 132 + cc4 * 4];
    dst[0] = v.x; dst[1] = v.y; dst[2] = v.z; dst[3] = v.w;
  }
  __syncthreads();
  int fl = t >> 1;   // 0..127 local feature
  int rq = t & 1;    // which 8-rank group
  float v[8];
#pragma unroll
  for (int i = 0; i < 8; ++i) v[i] = tile[(rq * 8 + i) * 132 + fl];
  size_t obase = (size_t)(fb + fl) * k + r0 + rq * 8;
  if (((k & 3) == 0) && (r0 + rq * 8 + 7 < k)) {
    *(float4*)(out + obase) = make_float4(v[0], v[1], v[2], v[3]);
    *(float4*)(out + obase + 4) = make_float4(v[4], v[5], v[6], v[7]);
  } else {
#pragma unroll
    for (int i = 0; i < 8; ++i)
      if (r0 + rq * 8 + i < k) out[obase + i] = v[i];
  }
}

extern "C" void kernel_launch(void* const* d_in, const int* in_sizes, int n_in,
                              void* d_out, int out_size, void* d_ws, size_t ws_size,
                              hipStream_t stream) {
  const float* embs = (const float*)d_in[0];
  const float* mask = (const float*)d_in[1];
  const float* scorer = (const float*)d_in[2];
  int F = in_sizes[2];      // 256
  int N = in_sizes[0] / F;  // 100000
  int k = out_size / F;     // 2000

  // keys live in d_out (N*4 = 400KB << 2MB); k5 overwrites all of d_out.
  uint32_t* keys = (uint32_t*)d_out;

  char* ws = (char*)d_ws;
  uint32_t* hdr = (uint32_t*)ws;              // 1KB: [2]=candidate count C
  uint32_t* ckey = (uint32_t*)(ws + 1024);    // 16KB
  uint32_t* cidx = ckey + CAP;                // 16KB
  uint32_t* oidx = cidx + CAP;                // 8KB

  k1_scores<<<(N + 255) / 256, 256, 0, stream>>>(embs, mask, scorer, keys, N);
  kB_select<<<1, 1024, 0, stream>>>(keys, hdr, ckey, cidx, N, k);
  k4_rank<<<(CAP + 15) / 16, 256, 0, stream>>>(ckey, cidx, hdr, oidx, k);
  k5_gather<<<dim3((k + 15) / 16, 2), 256, 0, stream>>>(embs, oidx, (float*)d_out, k);
}

// Round 8
// 60.368 us; speedup vs baseline: 1.2575x; 1.2575x over previous
//
#include <hip/hip_runtime.h>
#include <stdint.h>

// ---------------------------------------------------------------------------
// TopK: scores = (embs @ scorer)/sum(scorer) + mask; top-k rows; out = rows^T
// Ordering matches numpy/OpenBLAS sgemv_t fp32 bits exactly (verified
// R3/R5/R6, absmax=0): per row, 8 mod-8 fma chains (chain c sums elements
// c, c+8, ... ascending), reduced as ((L0+L4)+(L1+L5)) + ((L2+L6)+(L3+L7)).
// R8 = R6 structure (R7's single-block collapse serialized onto 1 CU and
// regressed; reverted) with two deltas:
//   k1 : LDS-staged COALESCED loads (512B segments) + 8 threads/row chains
//        + shfl_xor bracket (bit-exactness HW-verified in R5). No atomics.
//   k2 : shfl-based suffix scan, 3 barriers (logic HW-verified in R7).
// k1b (LDS-privatized histogram), k3, k4, k5 unchanged from R6.
// d_out layout during pipeline: keys @ [0,N*4); partials @ [out_size/2*4).
// k5 overwrites all of d_out. ws use: 41KB.
// ---------------------------------------------------------------------------

#define NBINS 8192   // 13-bit radix: sign + exp(8) + mantissa(4)
#define BIN_SHIFT 19
#define CAP 4096     // candidates: k + boundary bin (~600) << CAP
#define HPARTS 8

__device__ __forceinline__ uint32_t f2key(float f) {
  uint32_t b = __float_as_uint(f);
  return (b & 0x80000000u) ? ~b : (b | 0x80000000u);
}

// ---- kernel 1: 32 rows/block, 8 threads/row (one mod-8 chain each) --------
// Coalesced staging: each load instr covers 8 rows x 128B = 512B segments.
// No atomics, no histogram.
__global__ __launch_bounds__(256) void k1_scores(
    const float* __restrict__ embs, const float* __restrict__ mask,
    const float* __restrict__ scorer,
    uint32_t* __restrict__ keys, int N) {
  __shared__ float tile[32 * 132];
  __shared__ float sw[256];
  __shared__ float Ssh;
  int t = threadIdx.x;
  int r0 = blockIdx.x * 32;
  sw[t] = scorer[t];  // F == 256
  __syncthreads();
  if (t < 64) {
    double s = 0.0;
    for (int j = t; j < 256; j += 64) s += (double)sw[j];
#pragma unroll
    for (int off = 32; off >= 1; off >>= 1) s += __shfl_xor(s, off, 64);
    if (t == 0) Ssh = (float)s;  // f64 sum: order-independent at f32 grain
  }
  __syncthreads();
  float S = Ssh;
  int r = t >> 3, c = t & 7;
  float acc = 0.f;
  const float4* e4 = (const float4*)embs;
#pragma unroll
  for (int ch = 0; ch < 2; ++ch) {
    if (ch) __syncthreads();  // previous chunk's LDS reads complete
#pragma unroll
    for (int m = 0; m < 4; ++m) {      // 4*256 = 1024 f4 = 32 rows x 32 f4
      int flat = m * 256 + t;
      int rr = flat >> 5;              // 0..31
      int cc4 = flat & 31;             // 0..31
      int row = r0 + rr;
      float4 v = make_float4(0.f, 0.f, 0.f, 0.f);
      if (row < N) v = e4[(size_t)row * 64 + ch * 32 + cc4];  // 512B segs
      float* dst = &tile[rr * 132 + cc4 * 4];
      dst[0] = v.x; dst[1] = v.y; dst[2] = v.z; dst[3] = v.w;
    }
    __syncthreads();
#pragma unroll
    for (int sl = 0; sl < 16; ++sl) {  // ascending k within the chain
      acc = fmaf(tile[r * 132 + c + 8 * sl], sw[ch * 128 + c + 8 * sl], acc);
    }
  }
  // exact OpenBLAS bracket via commutative pair-sums (lanes stay in-row):
  float m1 = acc + __shfl_xor(acc, 4, 64);  // L_c + L_{c+4}
  float p1 = m1 + __shfl_xor(m1, 1, 64);    // (m0+m1) / (m2+m3)
  float dot = p1 + __shfl_xor(p1, 2, 64);   // ((m0+m1)+(m2+m3))
  int row = r0 + r;
  if (c == 0 && row < N) {
    float score = dot / S + mask[row];
    keys[row] = f2key(score);
  }
}

// ---- kernel 1b: LDS-privatized histogram -> HPARTS partial hists ----------
__global__ __launch_bounds__(256) void k1b_hist(
    const uint32_t* __restrict__ keys, uint32_t* __restrict__ partials,
    uint32_t* __restrict__ hdr, int N) {
  __shared__ uint32_t h[2][NBINS];  // 64 KB
  int t = threadIdx.x, b = blockIdx.x;
  for (int i = t; i < 2 * NBINS; i += 256) ((uint32_t*)h)[i] = 0u;
  if (b == 0 && t == 0) hdr[2] = 0;  // compact counter (k3 runs later)
  __syncthreads();
  int per = (N + HPARTS - 1) / HPARTS;
  int lo = b * per;
  int hi = lo + per; if (hi > N) hi = N;
  int sub = (t >> 7) & 1;
  for (int i = lo + t; i < hi; i += 256)
    atomicAdd(&h[sub][keys[i] >> BIN_SHIFT], 1u);
  __syncthreads();
  uint32_t* dst = partials + (size_t)b * NBINS;
  for (int i = t; i < NBINS; i += 256) dst[i] = h[0][i] + h[1][i];
}

// ---- kernel 2: reduce partials, shfl suffix-scan (3 barriers), find -------
__global__ __launch_bounds__(1024) void k2_findbucket(
    const uint32_t* __restrict__ partials, uint32_t* __restrict__ hdr, int k) {
  __shared__ uint32_t wtot[16];
  __shared__ uint32_t wsuf[16];
  int t = threadIdx.x;
  int lane = t & 63, wave = t >> 6;
  uint32_t rb[8];
#pragma unroll
  for (int j = 0; j < 8; ++j) rb[j] = 0u;
#pragma unroll
  for (int p = 0; p < HPARTS; ++p) {
    const uint4* q = (const uint4*)(partials + (size_t)p * NBINS) + t * 2;
    uint4 a = q[0], b2 = q[1];
    rb[0] += a.x;  rb[1] += a.y;  rb[2] += a.z;  rb[3] += a.w;
    rb[4] += b2.x; rb[5] += b2.y; rb[6] += b2.z; rb[7] += b2.w;
  }
  uint32_t p8 = rb[0] + rb[1] + rb[2] + rb[3] + rb[4] + rb[5] + rb[6] + rb[7];
  // wave-internal inclusive suffix scan (lane..63), no barriers:
  uint32_t x = p8;
#pragma unroll
  for (int off = 1; off < 64; off <<= 1) {
    uint32_t v = __shfl_down(x, off, 64);
    if (lane + off < 64) x += v;
  }
  if (lane == 0) wtot[wave] = x;
  __syncthreads();
  if (t < 16) {
    uint32_t y = wtot[t];
#pragma unroll
    for (int off = 1; off < 16; off <<= 1) {
      uint32_t v = __shfl_down(y, off, 64);
      if (t + off < 16) y += v;
    }
    wsuf[t] = y - wtot[t];  // sum of waves AFTER t
  }
  __syncthreads();
  uint32_t St = x + wsuf[wave];   // count of keys with bin >= 8t
  uint32_t above = St - p8;       // count with bin >= 8(t+1)
  if (above < (uint32_t)k && St >= (uint32_t)k) {  // unique thread
    uint32_t cum = above;
    for (int jj = 7; jj >= 0; --jj) {
      if (cum + rb[jj] >= (uint32_t)k) { hdr[0] = (uint32_t)(t * 8 + jj); hdr[1] = cum; break; }
      cum += rb[jj];
    }
  }
}

// ---- kernel 3: compact candidates (bin >= B), block-aggregated atomic ------
__global__ __launch_bounds__(256) void k3_compact(
    const uint32_t* __restrict__ keys, const uint32_t* __restrict__ hdr,
    uint32_t* __restrict__ ckey, uint32_t* __restrict__ cidx,
    uint32_t* __restrict__ counter, int N) {
  __shared__ uint32_t wcnt[4];
  __shared__ uint32_t wbase[4];
  __shared__ uint32_t blkbase;
  int i = blockIdx.x * 256 + threadIdx.x;
  int wave = threadIdx.x >> 6, lane = threadIdx.x & 63;
  uint32_t B = hdr[0];
  bool pred = false;
  uint32_t key = 0;
  if (i < N) {
    key = keys[i];
    pred = (key >> BIN_SHIFT) >= B;
  }
  unsigned long long ball = __ballot(pred);
  uint32_t prefix = (uint32_t)__popcll(ball & ((1ull << lane) - 1ull));
  if (lane == 0) wcnt[wave] = (uint32_t)__popcll(ball);
  __syncthreads();
  if (threadIdx.x == 0) {
    uint32_t tot = wcnt[0] + wcnt[1] + wcnt[2] + wcnt[3];
    blkbase = tot ? atomicAdd(counter, tot) : 0u;
    wbase[0] = 0;
    wbase[1] = wcnt[0];
    wbase[2] = wcnt[0] + wcnt[1];
    wbase[3] = wcnt[0] + wcnt[1] + wcnt[2];
  }
  __syncthreads();
  if (pred) {
    uint32_t pos = blkbase + wbase[wave] + prefix;
    if (pos < CAP) { ckey[pos] = key; cidx[pos] = (uint32_t)i; }
  }
}

// ---- kernel 4: exact rank, 4 candidates/wave, 16/block --------------------
__global__ __launch_bounds__(256) void k4_rank(
    const uint32_t* __restrict__ ckey, const uint32_t* __restrict__ cidx,
    const uint32_t* __restrict__ hdr, uint32_t* __restrict__ oidx, int k) {
  __shared__ uint32_t lk[CAP];
  __shared__ uint32_t li[CAP];
  uint32_t C = hdr[2];
  if (C > CAP) C = CAP;
  uint32_t base = blockIdx.x * 16u;
  if (base >= C) return;
  for (uint32_t j = threadIdx.x; j < C; j += 256u) {
    lk[j] = ckey[j];
    li[j] = cidx[j];
  }
  __syncthreads();
  int wave = threadIdx.x >> 6, lane = threadIdx.x & 63;
  uint32_t g0 = base + wave * 4u;
  uint32_t mk[4], mi[4], cnt[4];
#pragma unroll
  for (int q = 0; q < 4; ++q) {
    uint32_t g = g0 + q;
    bool valid = g < C;
    mk[q] = valid ? lk[g] : 0u;
    mi[q] = valid ? li[g] : 0xFFFFFFFFu;
    cnt[q] = 0u;
  }
  for (uint32_t j = lane; j < C; j += 64u) {
    uint32_t kj = lk[j], ij = li[j];
#pragma unroll
    for (int q = 0; q < 4; ++q)
      cnt[q] += (kj > mk[q] || (kj == mk[q] && ij < mi[q])) ? 1u : 0u;
  }
#pragma unroll
  for (int q = 0; q < 4; ++q) {
#pragma unroll
    for (int off = 32; off >= 1; off >>= 1) cnt[q] += __shfl_xor(cnt[q], off, 64);
  }
  if (lane == 0) {
#pragma unroll
    for (int q = 0; q < 4; ++q) {
      uint32_t g = g0 + q;
      if (g < C && cnt[q] < (uint32_t)k) oidx[cnt[q]] = mi[q];
    }
  }
}

// ---- kernel 5: gather + transpose; 16 ranks x 128 feats per block ----------
__global__ __launch_bounds__(256) void k5_gather(
    const float* __restrict__ embs, const uint32_t* __restrict__ oidx,
    float* __restrict__ out, int k) {
  __shared__ float tile[16 * 132];
  __shared__ uint32_t sidx[16];
  int t = threadIdx.x;
  int r0 = blockIdx.x * 16;
  int fb = blockIdx.y * 128;
  if (t < 16) sidx[t] = (r0 + t < k) ? oidx[r0 + t] : 0u;
  __syncthreads();
  const float4* e4 = (const float4*)embs;
#pragma unroll
  for (int m = 0; m < 2; ++m) {      // 2*256 = 512 f4 = 16 rows x 32 f4
    int flat = m * 256 + t;
    int rr = flat >> 5;
    int cc4 = flat & 31;
    float4 v = e4[(size_t)sidx[rr] * 64 + (fb >> 2) + cc4];
    float* dst = &tile[rr * 132 + cc4 * 4];
    dst[0] = v.x; dst[1] = v.y; dst[2] = v.z; dst[3] = v.w;
  }
  __syncthreads();
  int fl = t >> 1;   // 0..127 local feature
  int rq = t & 1;    // which 8-rank group
  float v[8];
#pragma unroll
  for (int i = 0; i < 8; ++i) v[i] = tile[(rq * 8 + i) * 132 + fl];
  size_t obase = (size_t)(fb + fl) * k + r0 + rq * 8;
  if (((k & 3) == 0) && (r0 + rq * 8 + 7 < k)) {
    *(float4*)(out + obase) = make_float4(v[0], v[1], v[2], v[3]);
    *(float4*)(out + obase + 4) = make_float4(v[4], v[5], v[6], v[7]);
  } else {
#pragma unroll
    for (int i = 0; i < 8; ++i)
      if (r0 + rq * 8 + i < k) out[obase + i] = v[i];
  }
}

extern "C" void kernel_launch(void* const* d_in, const int* in_sizes, int n_in,
                              void* d_out, int out_size, void* d_ws, size_t ws_size,
                              hipStream_t stream) {
  const float* embs = (const float*)d_in[0];
  const float* mask = (const float*)d_in[1];
  const float* scorer = (const float*)d_in[2];
  int F = in_sizes[2];      // 256
  int N = in_sizes[0] / F;  // 100000
  int k = out_size / F;     // 2000

  // d_out scratch layout (overwritten by k5 at the end):
  //   keys     @ [0, N*4)                 = 400 KB
  //   partials @ [out_size/2 * 4, +256KB)
  uint32_t* keys = (uint32_t*)d_out;
  uint32_t* partials = (uint32_t*)d_out + (out_size / 2);

  char* ws = (char*)d_ws;
  uint32_t* hdr = (uint32_t*)ws;                 // 1KB: [0]=B [1]=cumAbove [2]=C
  uint32_t* ckey = (uint32_t*)(ws + 1024);       // 16KB
  uint32_t* cidx = ckey + CAP;                   // 16KB
  uint32_t* oidx = cidx + CAP;                   // 8KB

  k1_scores<<<(N + 31) / 32, 256, 0, stream>>>(embs, mask, scorer, keys, N);
  k1b_hist<<<HPARTS, 256, 0, stream>>>(keys, partials, hdr, N);
  k2_findbucket<<<1, 1024, 0, stream>>>(partials, hdr, k);
  k3_compact<<<(N + 255) / 256, 256, 0, stream>>>(keys, hdr, ckey, cidx, &hdr[2], N);
  k4_rank<<<(CAP + 15) / 16, 256, 0, stream>>>(ckey, cidx, hdr, oidx, k);
  k5_gather<<<dim3((k + 15) / 16, 2), 256, 0, stream>>>(embs, oidx, (float*)d_out, k);
}